// Round 7
// baseline (1845.684 us; speedup 1.0000x reference)
//
#include <hip/hip_runtime.h>
#include <hip/hip_fp16.h>
#include <math.h>

#define B_ 8
#define T_ 32
#define N_ 10000
#define F_ 16
#define E_ 160000
#define HG_ 64
#define HT_ 128
#define BT_ (B_*T_)
#define PB_ 157          // ceil(N/64) node-chunks
#define EPS_ 1e-5f
#define NR2_ (PB_*64)    // 10048 padded node rows
#define NBTG_ 32         // 256 bt / 8 slots per group

typedef __attribute__((ext_vector_type(8))) _Float16 f16x8_t;  // 8 f16 = 4 VGPRs
typedef __attribute__((ext_vector_type(4))) float f32x4_t;     // MFMA acc

__device__ inline unsigned short f2h(float f) {
  return __half_as_ushort(__float2half(f));
}
__device__ inline unsigned pkrtz_u(float a, float b) {
  auto h = __builtin_amdgcn_cvt_pkrtz(a, b);
  unsigned u; __builtin_memcpy(&u, &h, 4); return u;
}
__device__ inline unsigned pack2h(float a, float b) {
  __half2 h = __floats2half2_rn(a, b);
  unsigned u; __builtin_memcpy(&u, &h, 4); return u;
}
__device__ inline __half2 u2h(unsigned u) {
  __half2 h; __builtin_memcpy(&h, &u, 4); return h;
}
__device__ inline unsigned h2u(__half2 h) {
  unsigned u; __builtin_memcpy(&u, &h, 4); return u;
}

// ---------------- CSR build ----------------
__global__ void k_zero(int* p, int n) {
  int i = blockIdx.x * 256 + threadIdx.x;
  if (i < n) p[i] = 0;
}

__global__ void k_deg(const int* __restrict__ dst, int* __restrict__ deg) {
  int e = blockIdx.x * 256 + threadIdx.x;
  if (e < E_) atomicAdd(&deg[dst[e]], 1);
}

__global__ void k_scan(const int* __restrict__ deg, int* __restrict__ row_ptr,
                       float* __restrict__ inv_deg) {
  __shared__ int part[256];
  int tid = threadIdx.x;
  int base = tid * 40;
  int s = 0;
  for (int i = 0; i < 40; i++) { int idx = base + i; if (idx < N_) s += deg[idx]; }
  part[tid] = s;
  __syncthreads();
  if (tid == 0) {
    int run = 0;
    for (int i = 0; i < 256; i++) { int v = part[i]; part[i] = run; run += v; }
  }
  __syncthreads();
  int run = part[tid];
  for (int i = 0; i < 40; i++) {
    int idx = base + i;
    if (idx < N_) {
      row_ptr[idx] = run;
      int d = deg[idx];
      run += d;
      inv_deg[idx] = 1.0f / fmaxf((float)d, 1.0f);
    } else if (idx == N_) {
      row_ptr[N_] = run;
    }
  }
}

__global__ void k_fill(const int* __restrict__ src, const int* __restrict__ dst,
                       const int* __restrict__ row_ptr, int* __restrict__ cursor,
                       int* __restrict__ col) {
  int e = blockIdx.x * 256 + threadIdx.x;
  if (e < E_) {
    int d = dst[e];
    int p = atomicAdd(&cursor[d], 1);
    col[row_ptr[d] + p] = src[e];
  }
}

// ---------------- weight prep (f16 fragments) ----------------
__global__ void k_prepw(const float* __restrict__ W2l, const float* __restrict__ W2r,
                        unsigned short* __restrict__ Wbf) {
  int idx = blockIdx.x * 256 + threadIdx.x;   // 8192 total
  if (idx >= 4 * 4 * 64 * 8) return;
  int q  = idx & 7;
  int l  = (idx >> 3) & 63;
  int ks = (idx >> 9) & 3;
  int w  = idx >> 11;
  int j = w * 16 + (l & 15);
  int k = ks * 32 + ((l >> 4) * 8) + q;
  float v = (k < 64) ? W2l[j * 64 + k] : W2r[j * 64 + (k - 64)];
  Wbf[idx] = f2h(v);
}

__global__ void k_prepw1(const float* __restrict__ W1l, const float* __restrict__ W1r,
                         unsigned short* __restrict__ Wb1) {
  int idx = blockIdx.x * 256 + threadIdx.x;   // 2048 total
  if (idx >= 4 * 64 * 8) return;
  int q = idx & 7;
  int l = (idx >> 3) & 63;
  int w = idx >> 9;
  int j = w * 16 + (l & 15);
  int k = ((l >> 4) * 8) + q;
  float v = (k < 16) ? W1l[j * 16 + k] : W1r[j * 16 + (k - 16)];
  Wb1[idx] = f2h(v);
}

// ---------------- x -> grouped layout xg[node][slot8][16] f32 ----------------
__global__ void k_xg(const float* __restrict__ x, float* __restrict__ xg,
                     int g0) {
  int i = blockIdx.x;
  int btgl = i / PB_, chunk = i % PB_;
  int t = threadIdx.x;
  int node = t >> 2, fq = t & 3;
  int ng = chunk * 64 + node;
  int nc = ng < N_ ? ng : N_ - 1;
  float* ob = xg + ((size_t)btgl * NR2_ + ng) * 128 + fq * 4;
#pragma unroll
  for (int slot = 0; slot < 8; ++slot) {
    int bt = (g0 + btgl) * 8 + slot;
    float4 v = *(const float4*)(x + ((size_t)bt * N_ + nc) * 16 + fq * 4);
    *(float4*)(ob + slot * 16) = v;
  }
}

// ---------------- layer-1 aggregate: per dst node, gather xg rows (512B) ----
// f32 accumulate (matches prior numerics). lane = (eo[1]|slot[3]|fq[2]).
__launch_bounds__(256, 8)
__global__ void k_agg1(const float* __restrict__ xg, const int* __restrict__ row_ptr,
                       const int* __restrict__ col, const float* __restrict__ inv_deg,
                       float* __restrict__ agg1) {
  int i = blockIdx.x;
  int btgl = i / PB_, chunk = i % PB_;
  int tid = threadIdx.x;
  int w = __builtin_amdgcn_readfirstlane(tid >> 6);
  int lane = tid & 63;
  int eo = lane >> 5, slot = (lane >> 2) & 7, fq = lane & 3;
  const float* xb = xg + (size_t)btgl * NR2_ * 128;
  float* ab = agg1 + (size_t)btgl * NR2_ * 128;
  int nbase = chunk * 64 + w * 16;
  unsigned off = (unsigned)slot * 16 + (unsigned)fq * 4;   // float units
  for (int nn = 0; nn < 16; ++nn) {
    int dn = nbase + nn;
    float4 acc = {0.f, 0.f, 0.f, 0.f};
    int dd = 0, s0 = 0; float iv = 0.f;
    if (dn < N_) { s0 = row_ptr[dn]; dd = row_ptr[dn + 1] - s0; iv = inv_deg[dn]; }
    for (int base = 0; base < dd; base += 64) {
      int cnt = dd - base; if (cnt > 64) cnt = 64;
      int cl = (lane < cnt) ? col[s0 + base + lane] : 0;
      for (int e = 0; e < cnt; e += 2) {
        int idx = e + eo;
        int s = __shfl(cl, idx);
        if (idx < cnt) {
          float4 v = *(const float4*)(xb + (size_t)s * 128 + off);
          acc.x += v.x; acc.y += v.y; acc.z += v.z; acc.w += v.w;
        }
      }
    }
    acc.x += __shfl_xor(acc.x, 32); acc.y += __shfl_xor(acc.y, 32);
    acc.z += __shfl_xor(acc.z, 32); acc.w += __shfl_xor(acc.w, 32);
    if (eo == 0) {
      acc.x *= iv; acc.y *= iv; acc.z *= iv; acc.w *= iv;
      *(float4*)(ab + (size_t)dn * 128 + off) = acc;
    }
  }
}

// ---------------- layer-2 aggregate: per dst node, gather h1g rows (1KB) ----
// half2 accumulate (matches prior numerics). lane = (slot[3]|fq3[3]).
__launch_bounds__(256, 8)
__global__ void k_agg2(const unsigned short* __restrict__ h1g, const int* __restrict__ row_ptr,
                       const int* __restrict__ col, const float* __restrict__ inv_deg,
                       unsigned short* __restrict__ agg2) {
  int i = blockIdx.x;
  int btgl = i / PB_, chunk = i % PB_;
  int tid = threadIdx.x;
  int w = __builtin_amdgcn_readfirstlane(tid >> 6);
  int lane = tid & 63;
  int slot = lane >> 3, fq3 = lane & 7;
  const char* hb = (const char*)(h1g + (size_t)btgl * NR2_ * 512);
  char* ab = (char*)(agg2 + (size_t)btgl * NR2_ * 512);
  int nbase = chunk * 64 + w * 16;
  unsigned off = (unsigned)slot * 128 + (unsigned)fq3 * 16;  // bytes
  for (int nn = 0; nn < 16; ++nn) {
    int dn = nbase + nn;
    __half2 a0 = __float2half2_rn(0.f), a1 = a0, a2 = a0, a3 = a0;
    int dd = 0, s0 = 0; float iv = 0.f;
    if (dn < N_) { s0 = row_ptr[dn]; dd = row_ptr[dn + 1] - s0; iv = inv_deg[dn]; }
    for (int base = 0; base < dd; base += 64) {
      int cnt = dd - base; if (cnt > 64) cnt = 64;
      int cl = (lane < cnt) ? col[s0 + base + lane] : 0;
      int e = 0;
      for (; e + 1 < cnt; e += 2) {
        int sA = __shfl(cl, e), sB = __shfl(cl, e + 1);
        uint4 vA = *(const uint4*)(hb + (((size_t)sA) << 10) + off);
        uint4 vB = *(const uint4*)(hb + (((size_t)sB) << 10) + off);
        a0 += u2h(vA.x); a1 += u2h(vA.y); a2 += u2h(vA.z); a3 += u2h(vA.w);
        a0 += u2h(vB.x); a1 += u2h(vB.y); a2 += u2h(vB.z); a3 += u2h(vB.w);
      }
      if (e < cnt) {
        int sA = __shfl(cl, e);
        uint4 vA = *(const uint4*)(hb + (((size_t)sA) << 10) + off);
        a0 += u2h(vA.x); a1 += u2h(vA.y); a2 += u2h(vA.z); a3 += u2h(vA.w);
      }
    }
    __half2 ivh = __float2half2_rn(iv);
    uint4 pk;
    pk.x = h2u(a0 * ivh); pk.y = h2u(a1 * ivh);
    pk.z = h2u(a2 * ivh); pk.w = h2u(a3 * ivh);
    *(uint4*)(ab + (((size_t)dn) << 10) + off) = pk;
  }
}

// ---------------- layer-1 transform: agg1 + x-self -> MFMA -> LN -> h1g ----
__launch_bounds__(256, 8)
__global__ void k_tr1(const float* __restrict__ x, const float* __restrict__ agg1,
                      const unsigned short* __restrict__ Wb1, const float* __restrict__ b1,
                      const float* __restrict__ g1, const float* __restrict__ be1,
                      unsigned short* __restrict__ h1g, int g0) {
  __shared__ __align__(16) unsigned short ZU[64 * 136];   // f16 Z1b[64][40] / f32 Zf[64][68]
  __shared__ float red[2][4][64];
  unsigned short* Z1b = ZU;
  float* Zf = (float*)ZU;
  int i = blockIdx.x;
  int btl = i / PB_, chunk = i % PB_;
  int bt = g0 * 8 + btl;
  int btgl = btl >> 3, slot = btl & 7;
  int tid = threadIdx.x;
  int w = __builtin_amdgcn_readfirstlane(tid >> 6);
  int lane = tid & 63;
  int n0 = chunk * 64;

  // ---- Phase A: coalesced reads of agg1 + x self; pack to f16 tile ----
  {
    int m = w * 16 + (lane >> 2), fq2 = lane & 3;
    int ng = n0 + m;
    const float* ab = agg1 + (size_t)btgl * NR2_ * 128;
    float4 av = *(const float4*)(ab + (size_t)ng * 128 + slot * 16 + fq2 * 4);
    float4 sv = {0.f, 0.f, 0.f, 0.f};
    if (ng < N_) sv = *(const float4*)(x + ((size_t)bt * N_ + ng) * 16 + fq2 * 4);
    uint2 pka;
    pka.x = pkrtz_u(av.x, av.y);  pka.y = pkrtz_u(av.z, av.w);
    *(uint2*)&Z1b[m * 40 + fq2 * 4] = pka;            // agg: k = fq2*4..+3
    uint2 pks;
    pks.x = pkrtz_u(sv.x, sv.y);  pks.y = pkrtz_u(sv.z, sv.w);
    *(uint2*)&Z1b[m * 40 + 16 + fq2 * 4] = pks;       // self: k = 16+..
  }
  __syncthreads();

  // ---- Phase B: one f16 MFMA per node-tile. Wave w owns j in [16w,16w+16). ----
  int g = lane >> 4, c = lane & 15;
  float bj = b1[w * 16 + c];
  f32x4_t accf[4];
#pragma unroll
  for (int mt = 0; mt < 4; ++mt) accf[mt] = (f32x4_t){bj, bj, bj, bj};
  f16x8_t bfr = ((const f16x8_t*)Wb1)[w * 64 + lane];
#pragma unroll
  for (int mt = 0; mt < 4; ++mt) {
    const f16x8_t* ap = (const f16x8_t*)&Z1b[(mt * 16 + c) * 40 + g * 8];
    accf[mt] = __builtin_amdgcn_mfma_f32_16x16x32_f16(*ap, bfr, accf[mt], 0, 0, 0);
  }
  __syncthreads();

  // C layout (HW-verified): col = lane&15, row = 4*(lane>>4)+reg.
#pragma unroll
  for (int mt = 0; mt < 4; ++mt) {
#pragma unroll
    for (int q = 0; q < 4; ++q) {
      int nodeq = mt * 16 + g * 4 + q;
      Zf[nodeq * 68 + w * 16 + c] = accf[mt][q];
    }
  }
  __syncthreads();

  // ---- Epilogue: lane = node m; wave w owns j-quarter [16w,16w+16) ----
  int m = lane;
  const float* zr = Zf + m * 68 + w * 16;
  float4 z0 = *(const float4*)(zr + 0);
  float4 z1 = *(const float4*)(zr + 4);
  float4 z2 = *(const float4*)(zr + 8);
  float4 z3 = *(const float4*)(zr + 12);
  float acc[16];
  acc[0] = z0.x; acc[1] = z0.y; acc[2] = z0.z; acc[3] = z0.w;
  acc[4] = z1.x; acc[5] = z1.y; acc[6] = z1.z; acc[7] = z1.w;
  acc[8] = z2.x; acc[9] = z2.y; acc[10] = z2.z; acc[11] = z2.w;
  acc[12] = z3.x; acc[13] = z3.y; acc[14] = z3.z; acc[15] = z3.w;

  float s1 = 0.f, s2 = 0.f;
#pragma unroll
  for (int jj = 0; jj < 16; ++jj) { s1 += acc[jj]; s2 += acc[jj] * acc[jj]; }
  red[0][w][m] = s1;
  red[1][w][m] = s2;
  __syncthreads();
  float mu = (red[0][0][m] + red[0][1][m] + red[0][2][m] + red[0][3][m]) * (1.f / 64.f);
  float ex2 = (red[1][0][m] + red[1][1][m] + red[1][2][m] + red[1][3][m]) * (1.f / 64.f);
  float var = fmaxf(ex2 - mu * mu, 0.f);
  float rs = rsqrtf(var + EPS_);

  int nAbs = n0 + m;
  unsigned short* dst = h1g + ((size_t)btgl * NR2_ + nAbs) * 512 + slot * 64 + w * 16;
  if (nAbs < N_) {
#pragma unroll
    for (int jj = 0; jj < 16; ++jj)
      acc[jj] = fmaxf((acc[jj] - mu) * rs * g1[w * 16 + jj] + be1[w * 16 + jj], 0.f);
    uint4 pa, pb;
    pa.x = pack2h(acc[0], acc[1]);  pa.y = pack2h(acc[2], acc[3]);
    pa.z = pack2h(acc[4], acc[5]);  pa.w = pack2h(acc[6], acc[7]);
    pb.x = pack2h(acc[8], acc[9]);  pb.y = pack2h(acc[10], acc[11]);
    pb.z = pack2h(acc[12], acc[13]); pb.w = pack2h(acc[14], acc[15]);
    *(uint4*)dst = pa;
    *(uint4*)(dst + 8) = pb;
  } else {
    uint4 zz = {0, 0, 0, 0};
    *(uint4*)dst = zz;
    *(uint4*)(dst + 8) = zz;
  }
}

// ---------------- layer-2 transform: agg2 + h1g-self -> MFMA -> LN -> Hsum ----
__launch_bounds__(256, 8)
__global__ void k_tr2(const unsigned short* __restrict__ h1g, const unsigned short* __restrict__ agg2,
                      const unsigned short* __restrict__ Wbf, const float* __restrict__ b2,
                      const float* __restrict__ g2, const float* __restrict__ be2,
                      float* __restrict__ Hsum, int g0) {
  __shared__ __align__(16) unsigned short Zb[64 * 136];   // f16 / aliased fp32
  __shared__ float red[2][4][64];
  float* Zf = (float*)Zb;
  int i = blockIdx.x;
  int btl = i / PB_, chunk = i % PB_;
  int bt = g0 * 8 + btl;
  int btgl = btl >> 3, slot = btl & 7;
  int b = bt / T_, t = bt % T_;
  int tid = threadIdx.x;
  int w = __builtin_amdgcn_readfirstlane(tid >> 6);
  int lane = tid & 63;
  int n0 = chunk * 64;

  // ---- Phase A: coalesced copies agg2 -> Zb (agg half), h1g -> Zb (self) ----
  {
    int mh = lane >> 3, fq3 = lane & 7;
    const char* ab = (const char*)(agg2 + (size_t)btgl * NR2_ * 512);
    const char* hb = (const char*)(h1g + (size_t)btgl * NR2_ * 512);
    unsigned off = (unsigned)slot * 128 + (unsigned)fq3 * 16;
#pragma unroll
    for (int p = 0; p < 2; ++p) {
      int m = w * 16 + p * 8 + mh;
      size_t ro = (((size_t)(n0 + m)) << 10) + off;
      uint4 va = *(const uint4*)(ab + ro);
      uint4 vs = *(const uint4*)(hb + ro);
      *(uint4*)&Zb[m * 136 + fq3 * 8] = va;           // agg: k = fq3*8..+7
      *(uint4*)&Zb[m * 136 + 64 + fq3 * 8] = vs;      // self: k = 64+..
    }
  }
  __syncthreads();

  // ---- Phase B: f16 MFMA. Wave w owns output features j in [16w, 16w+16). ----
  int g = lane >> 4, c = lane & 15;
  const f16x8_t* Wb8 = (const f16x8_t*)Wbf;
  float bj = b2[w * 16 + c];
  f32x4_t accf[4];
#pragma unroll
  for (int mt = 0; mt < 4; ++mt) accf[mt] = (f32x4_t){bj, bj, bj, bj};
#pragma unroll
  for (int ks = 0; ks < 4; ++ks) {
    f16x8_t bfr = Wb8[(w * 4 + ks) * 64 + lane];
#pragma unroll
    for (int mt = 0; mt < 4; ++mt) {
      const f16x8_t* ap = (const f16x8_t*)&Zb[(mt * 16 + c) * 136 + ks * 32 + g * 8];
      accf[mt] = __builtin_amdgcn_mfma_f32_16x16x32_f16(*ap, bfr, accf[mt], 0, 0, 0);
    }
  }
  __syncthreads();

#pragma unroll
  for (int mt = 0; mt < 4; ++mt) {
#pragma unroll
    for (int q = 0; q < 4; ++q) {
      int nodeq = mt * 16 + g * 4 + q;
      Zf[nodeq * 68 + w * 16 + c] = accf[mt][q];
    }
  }
  __syncthreads();

  // ---- Epilogue ----
  int m = lane;
  float* zr = Zf + m * 68 + w * 16;
  float4 z0 = *(const float4*)(zr + 0);
  float4 z1 = *(const float4*)(zr + 4);
  float4 z2 = *(const float4*)(zr + 8);
  float4 z3 = *(const float4*)(zr + 12);
  float acc[16];
  acc[0] = z0.x; acc[1] = z0.y; acc[2] = z0.z; acc[3] = z0.w;
  acc[4] = z1.x; acc[5] = z1.y; acc[6] = z1.z; acc[7] = z1.w;
  acc[8] = z2.x; acc[9] = z2.y; acc[10] = z2.z; acc[11] = z2.w;
  acc[12] = z3.x; acc[13] = z3.y; acc[14] = z3.z; acc[15] = z3.w;

  float s1 = 0.f, s2 = 0.f;
#pragma unroll
  for (int jj = 0; jj < 16; ++jj) { s1 += acc[jj]; s2 += acc[jj] * acc[jj]; }
  red[0][w][m] = s1;
  red[1][w][m] = s2;
  __syncthreads();
  float mu = (red[0][0][m] + red[0][1][m] + red[0][2][m] + red[0][3][m]) * (1.f / 64.f);
  float ex2 = (red[1][0][m] + red[1][1][m] + red[1][2][m] + red[1][3][m]) * (1.f / 64.f);
  float var = fmaxf(ex2 - mu * mu, 0.f);
  float rs = rsqrtf(var + EPS_);

  bool okm = (n0 + m) < N_;
#pragma unroll
  for (int jj = 0; jj < 16; ++jj) {
    float hv = fmaxf((acc[jj] - mu) * rs * g2[w * 16 + jj] + be2[w * 16 + jj], 0.f);
    acc[jj] = okm ? hv : 0.f;
  }
  float4 o0 = {acc[0], acc[1], acc[2], acc[3]};
  float4 o1 = {acc[4], acc[5], acc[6], acc[7]};
  float4 o2 = {acc[8], acc[9], acc[10], acc[11]};
  float4 o3 = {acc[12], acc[13], acc[14], acc[15]};
  *(float4*)(zr + 0) = o0;  *(float4*)(zr + 4) = o1;
  *(float4*)(zr + 8) = o2;  *(float4*)(zr + 12) = o3;
  __syncthreads();

  float cs = 0.f;
#pragma unroll
  for (int ii = 0; ii < 16; ++ii) cs += Zf[(w * 16 + ii) * 68 + lane];
  red[0][w][lane] = cs;
  __syncthreads();
  if (w == 0) {
    float tot = red[0][0][lane] + red[0][1][lane] + red[0][2][lane] + red[0][3][lane];
    atomicAdd(&Hsum[(t * B_ + b) * HG_ + lane], tot);
  }
}

// ---------------- GRU input precompute: GI[t][b][384] ----------------
__global__ void k_gi(const float* __restrict__ Hsum, const float* __restrict__ W_ih,
                     const float* __restrict__ b_ih, float* __restrict__ GI) {
  __shared__ float xv[64];
  int tb = blockIdx.x;
  int tid = threadIdx.x;
  if (tid < 64) xv[tid] = Hsum[tb * 64 + tid] * (1.0f / (float)N_);
  __syncthreads();
  float g = b_ih[tid];
  const float4* W4 = (const float4*)(W_ih + tid * 64);
  const float4* x4 = (const float4*)xv;
#pragma unroll
  for (int q = 0; q < 16; q++) {
    float4 w = W4[q], xq = x4[q];
    g = fmaf(xq.x, w.x, g); g = fmaf(xq.y, w.y, g);
    g = fmaf(xq.z, w.z, g); g = fmaf(xq.w, w.w, g);
  }
  GI[tb * 384 + tid] = g;
}

// ---------------- sequential GRU + head; one block per batch ----------------
__global__ void k_gru(const float* __restrict__ GI, const float* __restrict__ W_hh,
                      const float* __restrict__ b_hh, const float* __restrict__ Wh,
                      const float* __restrict__ bh, float* __restrict__ out) {
  __shared__ float hL[128];
  __shared__ float ghL[384];
  __shared__ float red[128];
  int b = blockIdx.x, tid = threadIdx.x;
  if (tid < 128) hL[tid] = 0.f;
  float bhh = b_hh[tid];
  const float4* W4 = (const float4*)(W_hh + tid * 128);
  for (int t = 0; t < T_; ++t) {
    __syncthreads();
    float g = bhh;
    const float4* h4 = (const float4*)hL;
#pragma unroll
    for (int q = 0; q < 32; q++) {
      float4 w = W4[q], hv = h4[q];
      g = fmaf(hv.x, w.x, g); g = fmaf(hv.y, w.y, g);
      g = fmaf(hv.z, w.z, g); g = fmaf(hv.w, w.w, g);
    }
    ghL[tid] = g;
    __syncthreads();
    float hnew = 0.f;
    if (tid < 128) {
      const float* gi = GI + (t * B_ + b) * 384;
      float rr = 1.f / (1.f + expf(-(gi[tid] + ghL[tid])));
      float zz = 1.f / (1.f + expf(-(gi[128 + tid] + ghL[128 + tid])));
      float nn = tanhf(gi[256 + tid] + rr * ghL[256 + tid]);
      hnew = (1.f - zz) * nn + zz * hL[tid];
    }
    __syncthreads();
    if (tid < 128) hL[tid] = hnew;
  }
  __syncthreads();
  if (tid < 128) red[tid] = hL[tid] * Wh[tid];
  __syncthreads();
  if (tid == 0) {
    float s = bh[0];
    for (int k = 0; k < 128; k++) s += red[k];
    out[b] = s;
  }
}

extern "C" void kernel_launch(void* const* d_in, const int* in_sizes, int n_in,
                              void* d_out, int out_size, void* d_ws, size_t ws_size,
                              hipStream_t stream) {
  const float* x    = (const float*)d_in[0];
  const int*   ei   = (const int*)d_in[1];
  const float* W1l  = (const float*)d_in[2];
  const float* b1   = (const float*)d_in[3];
  const float* W1r  = (const float*)d_in[4];
  const float* g1   = (const float*)d_in[5];
  const float* be1  = (const float*)d_in[6];
  const float* W2l  = (const float*)d_in[7];
  const float* b2   = (const float*)d_in[8];
  const float* W2r  = (const float*)d_in[9];
  const float* g2   = (const float*)d_in[10];
  const float* be2  = (const float*)d_in[11];
  const float* W_ih = (const float*)d_in[12];
  const float* W_hh = (const float*)d_in[13];
  const float* b_ih = (const float*)d_in[14];
  const float* b_hh = (const float*)d_in[15];
  const float* Wh   = (const float*)d_in[16];
  const float* bh   = (const float*)d_in[17];
  float* out = (float*)d_out;

  char* ws = (char*)d_ws;
  size_t off = 0;
  auto alloc = [&](size_t bytes) { void* p = ws + off; off += (bytes + 255) & ~(size_t)255; return p; };
  int*   deg     = (int*)alloc((size_t)N_ * 4);
  int*   row_ptr = (int*)alloc((size_t)(N_ + 1) * 4);
  int*   cursor  = (int*)alloc((size_t)N_ * 4);
  int*   col     = (int*)alloc((size_t)E_ * 4);
  float* ivd     = (float*)alloc((size_t)N_ * 4);
  float* Hsum    = (float*)alloc((size_t)BT_ * HG_ * 4);
  float* GI      = (float*)alloc((size_t)BT_ * 384 * 4);
  unsigned short* Wbf = (unsigned short*)alloc((size_t)4 * 4 * 64 * 8 * 2);
  unsigned short* Wb1 = (unsigned short*)alloc((size_t)4 * 64 * 8 * 2);
  size_t fixed = off;

  // grouped buffers, SG bt-groups at a time
  size_t xg_b = (size_t)NR2_ * 128 * 4;   // 5.14 MB per btg (f32 [node][slot][16])
  size_t a1_b = xg_b;
  size_t h1_b = (size_t)NR2_ * 512 * 2;   // 10.29 MB per btg (f16 [node][slot][64])
  size_t a2_b = h1_b;
  size_t per = xg_b + a1_b + h1_b + a2_b; // 30.87 MB
  size_t cap = (ws_size > fixed) ? (ws_size - fixed) : 0;
  int SG = (int)(cap / per);
  if (SG > NBTG_) SG = NBTG_;
  if (SG < 1) SG = 1;
  float* xg = (float*)(ws + fixed);
  float* agg1 = (float*)((char*)xg + (size_t)SG * xg_b);
  unsigned short* h1g = (unsigned short*)((char*)agg1 + (size_t)SG * a1_b);
  unsigned short* agg2 = (unsigned short*)((char*)h1g + (size_t)SG * h1_b);

  int zn = (int)(fixed / 4);
  k_zero<<<(zn + 255) / 256, 256, 0, stream>>>((int*)ws, zn);

  const int* srcp = ei;
  const int* dstp = ei + E_;
  k_deg<<<(E_ + 255) / 256, 256, 0, stream>>>(dstp, deg);
  k_scan<<<1, 256, 0, stream>>>(deg, row_ptr, ivd);
  k_fill<<<(E_ + 255) / 256, 256, 0, stream>>>(srcp, dstp, row_ptr, cursor, col);
  k_prepw<<<32, 256, 0, stream>>>(W2l, W2r, Wbf);
  k_prepw1<<<8, 256, 0, stream>>>(W1l, W1r, Wb1);

  for (int g0 = 0; g0 < NBTG_; g0 += SG) {
    int nb = NBTG_ - g0 < SG ? NBTG_ - g0 : SG;
    k_xg  <<<nb * PB_, 256, 0, stream>>>(x, xg, g0);
    k_agg1<<<nb * PB_, 256, 0, stream>>>(xg, row_ptr, col, ivd, agg1);
    k_tr1 <<<nb * 8 * PB_, 256, 0, stream>>>(x, agg1, Wb1, b1, g1, be1, h1g, g0);
    k_agg2<<<nb * PB_, 256, 0, stream>>>(h1g, row_ptr, col, ivd, agg2);
    k_tr2 <<<nb * 8 * PB_, 256, 0, stream>>>(h1g, agg2, Wbf, b2, g2, be2, Hsum, g0);
  }
  k_gi<<<BT_, 384, 0, stream>>>(Hsum, W_ih, b_ih, GI);
  k_gru<<<B_, 384, 0, stream>>>(GI, W_hh, b_hh, Wh, bh, out);
}

// Round 8
// 1677.690 us; speedup vs baseline: 1.1001x; 1.1001x over previous
//
#include <hip/hip_runtime.h>
#include <hip/hip_fp16.h>
#include <math.h>

#define B_ 8
#define T_ 32
#define N_ 10000
#define F_ 16
#define E_ 160000
#define HG_ 64
#define HT_ 128
#define BT_ (B_*T_)
#define PB_ 157   // ceil(N/64) node-chunks per bt
#define EPS_ 1e-5f

typedef __attribute__((ext_vector_type(8))) _Float16 f16x8_t;  // 8 f16 = 4 VGPRs
typedef __attribute__((ext_vector_type(4))) float f32x4_t;     // MFMA acc

__device__ inline unsigned short f2h(float f) {
  return __half_as_ushort(__float2half(f));
}
__device__ inline unsigned pkrtz_u(float a, float b) {
  auto h = __builtin_amdgcn_cvt_pkrtz(a, b);
  unsigned u; __builtin_memcpy(&u, &h, 4); return u;
}
__device__ inline unsigned pack2h(float a, float b) {
  __half2 h = __floats2half2_rn(a, b);
  unsigned u; __builtin_memcpy(&u, &h, 4); return u;
}
__device__ inline __half2 u2h(unsigned u) {
  __half2 h; __builtin_memcpy(&h, &u, 4); return h;
}
__device__ inline unsigned h2u(__half2 h) {
  unsigned u; __builtin_memcpy(&u, &h, 4); return u;
}
__device__ inline void bflyh(__half2& a, int m) {
  unsigned u = (unsigned)__shfl_xor((int)h2u(a), m);
  a += u2h(u);
}

// ---------------- CSR build ----------------
__global__ void k_zero(int* p, int n) {
  int i = blockIdx.x * 256 + threadIdx.x;
  if (i < n) p[i] = 0;
}

__global__ void k_deg(const int* __restrict__ dst, int* __restrict__ deg) {
  int e = blockIdx.x * 256 + threadIdx.x;
  if (e < E_) atomicAdd(&deg[dst[e]], 1);
}

__global__ void k_scan(const int* __restrict__ deg, int* __restrict__ row_ptr,
                       float* __restrict__ inv_deg) {
  __shared__ int part[256];
  int tid = threadIdx.x;
  int base = tid * 40;
  int s = 0;
  for (int i = 0; i < 40; i++) { int idx = base + i; if (idx < N_) s += deg[idx]; }
  part[tid] = s;
  __syncthreads();
  if (tid == 0) {
    int run = 0;
    for (int i = 0; i < 256; i++) { int v = part[i]; part[i] = run; run += v; }
  }
  __syncthreads();
  int run = part[tid];
  for (int i = 0; i < 40; i++) {
    int idx = base + i;
    if (idx < N_) {
      row_ptr[idx] = run;
      int d = deg[idx];
      run += d;
      inv_deg[idx] = 1.0f / fmaxf((float)d, 1.0f);
    } else if (idx == N_) {
      row_ptr[N_] = run;
    }
  }
}

__global__ void k_fill(const int* __restrict__ src, const int* __restrict__ dst,
                       const int* __restrict__ row_ptr, int* __restrict__ cursor,
                       int* __restrict__ col) {
  int e = blockIdx.x * 256 + threadIdx.x;
  if (e < E_) {
    int d = dst[e];
    int p = atomicAdd(&cursor[d], 1);
    col[row_ptr[d] + p] = src[e];
  }
}

// ---------------- weight prep (f16 fragments) ----------------
__global__ void k_prepw(const float* __restrict__ W2l, const float* __restrict__ W2r,
                        unsigned short* __restrict__ Wbf) {
  int idx = blockIdx.x * 256 + threadIdx.x;   // 8192 total
  if (idx >= 4 * 4 * 64 * 8) return;
  int q  = idx & 7;
  int l  = (idx >> 3) & 63;
  int ks = (idx >> 9) & 3;
  int w  = idx >> 11;
  int j = w * 16 + (l & 15);
  int k = ks * 32 + ((l >> 4) * 8) + q;
  float v = (k < 64) ? W2l[j * 64 + k] : W2r[j * 64 + (k - 64)];
  Wbf[idx] = f2h(v);
}

__global__ void k_prepw1(const float* __restrict__ W1l, const float* __restrict__ W1r,
                         unsigned short* __restrict__ Wb1) {
  int idx = blockIdx.x * 256 + threadIdx.x;   // 2048 total
  if (idx >= 4 * 64 * 8) return;
  int q = idx & 7;
  int l = (idx >> 3) & 63;
  int w = idx >> 9;
  int j = w * 16 + (l & 15);
  int k = ((l >> 4) * 8) + q;
  float v = (k < 16) ? W1l[j * 16 + k] : W1r[j * 16 + (k - 16)];
  Wb1[idx] = f2h(v);
}

// ---------------- SAGE layer 1: wave-per-node gather + MFMA + LN -> h1 ----
// Gather: lane = (e4[4] | fq2[2]); 16 edges x 64B rows per load instr.
// XCD-pinned bt (swz): blocks of one bt stay on one XCD -> x slab (640KB) L2-hot.
__launch_bounds__(256, 8)
__global__ void k_s1(const float* __restrict__ x, const int* __restrict__ row_ptr,
                     const int* __restrict__ col, const float* __restrict__ inv_deg,
                     const unsigned short* __restrict__ Wb1, const float* __restrict__ b1,
                     const float* __restrict__ g1, const float* __restrict__ be1,
                     unsigned short* __restrict__ h1, int bt0, int swz) {
  __shared__ __align__(16) unsigned short ZU[64 * 136];   // f16 Z1b[64][40] / f32 Zf[64][68]
  __shared__ float red[2][4][64];
  unsigned short* Z1b = ZU;
  float* Zf = (float*)ZU;
  int i = blockIdx.x;
  int btl, chunk;
  if (swz) { int xcd = i & 7; int jj = i >> 3; btl = (jj / PB_) * 8 + xcd; chunk = jj % PB_; }
  else     { btl = i / PB_; chunk = i % PB_; }
  int bt = bt0 + btl;
  const float4* xb = (const float4*)(x + (size_t)bt * (N_ * F_));   // node row = 4 float4
  int tid = threadIdx.x;
  int w = __builtin_amdgcn_readfirstlane(tid >> 6);
  int lane = tid & 63;
  int n0 = chunk * 64;
  int fq2 = lane & 3, e4 = lane >> 2;

  // stage per-node CSR info for this wave's 16 nodes (lanes 0..15)
  int nloc = n0 + w * 16 + (lane & 15);
  int rp = 0, dS = 0; float ivS = 0.f;
  if (nloc < N_) { rp = row_ptr[nloc]; dS = row_ptr[nloc + 1] - rp; ivS = inv_deg[nloc]; }

  // ---- Phase A: gather-average, one dst node per wave-iteration ----
  for (int nn = 0; nn < 16; ++nn) {
    int s0 = __shfl(rp, nn), dd = __shfl(dS, nn);
    float iv = __shfl(ivS, nn);
    float4 acc = {0.f, 0.f, 0.f, 0.f};
    for (int base = 0; base < dd; base += 64) {
      int cnt = dd - base; if (cnt > 64) cnt = 64;
      int cl = (lane < cnt) ? col[s0 + base + lane] : 0;
      for (int e = 0; e < cnt; e += 16) {
        int idx = e + e4;
        int s = __shfl(cl, idx);
        if (idx < cnt) {
          float4 v = xb[(size_t)s * 4 + fq2];
          acc.x += v.x; acc.y += v.y; acc.z += v.z; acc.w += v.w;
        }
      }
    }
#pragma unroll
    for (int mk = 4; mk < 64; mk <<= 1) {
      acc.x += __shfl_xor(acc.x, mk); acc.y += __shfl_xor(acc.y, mk);
      acc.z += __shfl_xor(acc.z, mk); acc.w += __shfl_xor(acc.w, mk);
    }
    if (e4 == 0) {   // lanes 0..3 hold fq2 sub-blocks
      uint2 pk;
      pk.x = pkrtz_u(acc.x * iv, acc.y * iv);
      pk.y = pkrtz_u(acc.z * iv, acc.w * iv);
      *(uint2*)&Z1b[(w * 16 + nn) * 40 + fq2 * 4] = pk;        // agg: k = fq2*4..+3
    }
  }
  // self rows (coalesced: 16 nodes per instr)
  {
    int m = w * 16 + (lane >> 2);
    int ng = n0 + m;
    float4 sv = {0.f, 0.f, 0.f, 0.f};
    if (ng < N_) sv = xb[(size_t)ng * 4 + fq2];
    uint2 pk;
    pk.x = pkrtz_u(sv.x, sv.y);
    pk.y = pkrtz_u(sv.z, sv.w);
    *(uint2*)&Z1b[m * 40 + 16 + fq2 * 4] = pk;                 // self: k = 16+..
  }
  __syncthreads();

  // ---- Phase B: one f16 MFMA per node-tile. Wave w owns j in [16w,16w+16). ----
  int g = lane >> 4, c = lane & 15;
  float bj = b1[w * 16 + c];
  f32x4_t accf[4];
#pragma unroll
  for (int mt = 0; mt < 4; ++mt) accf[mt] = (f32x4_t){bj, bj, bj, bj};
  f16x8_t bfr = ((const f16x8_t*)Wb1)[w * 64 + lane];
#pragma unroll
  for (int mt = 0; mt < 4; ++mt) {
    const f16x8_t* ap = (const f16x8_t*)&Z1b[(mt * 16 + c) * 40 + g * 8];
    accf[mt] = __builtin_amdgcn_mfma_f32_16x16x32_f16(*ap, bfr, accf[mt], 0, 0, 0);
  }
  __syncthreads();   // all waves done reading Z1b before aliased fp32 writes

  // C layout (HW-verified): col = lane&15, row = 4*(lane>>4)+reg.
#pragma unroll
  for (int mt = 0; mt < 4; ++mt) {
#pragma unroll
    for (int q = 0; q < 4; ++q) {
      int nodeq = mt * 16 + g * 4 + q;
      Zf[nodeq * 68 + w * 16 + c] = accf[mt][q];
    }
  }
  __syncthreads();

  // ---- Epilogue: lane = node m; wave w owns j-quarter [16w,16w+16) ----
  int m = lane;
  const float* zr = Zf + m * 68 + w * 16;
  float4 z0 = *(const float4*)(zr + 0);
  float4 z1 = *(const float4*)(zr + 4);
  float4 z2 = *(const float4*)(zr + 8);
  float4 z3 = *(const float4*)(zr + 12);
  float acc[16];
  acc[0] = z0.x; acc[1] = z0.y; acc[2] = z0.z; acc[3] = z0.w;
  acc[4] = z1.x; acc[5] = z1.y; acc[6] = z1.z; acc[7] = z1.w;
  acc[8] = z2.x; acc[9] = z2.y; acc[10] = z2.z; acc[11] = z2.w;
  acc[12] = z3.x; acc[13] = z3.y; acc[14] = z3.z; acc[15] = z3.w;

  float s1 = 0.f, s2 = 0.f;
#pragma unroll
  for (int jj = 0; jj < 16; ++jj) { s1 += acc[jj]; s2 += acc[jj] * acc[jj]; }
  red[0][w][m] = s1;
  red[1][w][m] = s2;
  __syncthreads();
  float mu = (red[0][0][m] + red[0][1][m] + red[0][2][m] + red[0][3][m]) * (1.f / 64.f);
  float ex2 = (red[1][0][m] + red[1][1][m] + red[1][2][m] + red[1][3][m]) * (1.f / 64.f);
  float var = fmaxf(ex2 - mu * mu, 0.f);
  float rs = rsqrtf(var + EPS_);

  int nAbs = n0 + m;
  if (nAbs < N_) {
#pragma unroll
    for (int jj = 0; jj < 16; ++jj)
      acc[jj] = fmaxf((acc[jj] - mu) * rs * g1[w * 16 + jj] + be1[w * 16 + jj], 0.f);
    uint4 pa, pb;
    pa.x = pack2h(acc[0], acc[1]);  pa.y = pack2h(acc[2], acc[3]);
    pa.z = pack2h(acc[4], acc[5]);  pa.w = pack2h(acc[6], acc[7]);
    pb.x = pack2h(acc[8], acc[9]);  pb.y = pack2h(acc[10], acc[11]);
    pb.z = pack2h(acc[12], acc[13]); pb.w = pack2h(acc[14], acc[15]);
    unsigned short* dst = h1 + ((size_t)btl * N_ + nAbs) * HG_ + w * 16;
    *(uint4*)dst = pa;
    *(uint4*)(dst + 8) = pb;
  }
}

// ---------------- SAGE layer 2: wave-per-node gather + MFMA + LN -> Hsum ----
// Gather: lane = (e3[3] | fq3[3]); 8 edges x 128B rows per load instr.
// Same XCD pin as k_s1 -> h1 slab (1.28MB) L2-hot.
__launch_bounds__(256, 8)
__global__ void k_s2(const unsigned short* __restrict__ h1, const int* __restrict__ row_ptr,
                     const int* __restrict__ col, const float* __restrict__ inv_deg,
                     const unsigned short* __restrict__ Wbf, const float* __restrict__ b2,
                     const float* __restrict__ g2, const float* __restrict__ be2,
                     float* __restrict__ Hsum, int bt0, int swz) {
  __shared__ __align__(16) unsigned short Zb[64 * 136];   // f16 / aliased fp32
  __shared__ float red[2][4][64];
  float* Zf = (float*)Zb;
  int i = blockIdx.x;
  int btl, chunk;
  if (swz) { int xcd = i & 7; int jj = i >> 3; btl = (jj / PB_) * 8 + xcd; chunk = jj % PB_; }
  else     { btl = i / PB_; chunk = i % PB_; }
  int bt = bt0 + btl;
  int b = bt / T_, t = bt % T_;
  const char* hb = (const char*)(h1 + (size_t)btl * ((size_t)N_ * HG_));  // row = 128 B
  int tid = threadIdx.x;
  int w = __builtin_amdgcn_readfirstlane(tid >> 6);
  int lane = tid & 63;
  int n0 = chunk * 64;
  int fq3 = lane & 7, e3 = lane >> 3;
  unsigned foff = (unsigned)fq3 * 16;

  // stage per-node CSR info (lanes 0..15)
  int nloc = n0 + w * 16 + (lane & 15);
  int rp = 0, dS = 0; float ivS = 0.f;
  if (nloc < N_) { rp = row_ptr[nloc]; dS = row_ptr[nloc + 1] - rp; ivS = inv_deg[nloc]; }

  // ---- Phase A: gather-average, one dst node per wave-iteration ----
  for (int nn = 0; nn < 16; ++nn) {
    int s0 = __shfl(rp, nn), dd = __shfl(dS, nn);
    float iv = __shfl(ivS, nn);
    __half2 a0 = __float2half2_rn(0.f), a1 = a0, a2 = a0, a3 = a0;
    for (int base = 0; base < dd; base += 64) {
      int cnt = dd - base; if (cnt > 64) cnt = 64;
      int cl = (lane < cnt) ? col[s0 + base + lane] : 0;
      for (int e = 0; e < cnt; e += 8) {
        int idx = e + e3;
        int s = __shfl(cl, idx);
        if (idx < cnt) {
          uint4 v = *(const uint4*)(hb + (((size_t)s) << 7) + foff);
          a0 += u2h(v.x); a1 += u2h(v.y); a2 += u2h(v.z); a3 += u2h(v.w);
        }
      }
    }
    bflyh(a0, 8);  bflyh(a1, 8);  bflyh(a2, 8);  bflyh(a3, 8);
    bflyh(a0, 16); bflyh(a1, 16); bflyh(a2, 16); bflyh(a3, 16);
    bflyh(a0, 32); bflyh(a1, 32); bflyh(a2, 32); bflyh(a3, 32);
    if (e3 == 0) {   // lanes 0..7 hold fq3 sub-blocks
      __half2 ivh = __float2half2_rn(iv);
      uint4 pk;
      pk.x = h2u(a0 * ivh); pk.y = h2u(a1 * ivh);
      pk.z = h2u(a2 * ivh); pk.w = h2u(a3 * ivh);
      *(uint4*)&Zb[(w * 16 + nn) * 136 + fq3 * 8] = pk;        // agg: k = fq3*8..+7
    }
  }
  // self rows (coalesced: 8 nodes per instr, 2 instrs)
#pragma unroll
  for (int p = 0; p < 2; ++p) {
    int m = w * 16 + p * 8 + e3;
    int ng = n0 + m;
    uint4 sv = {0, 0, 0, 0};
    if (ng < N_) sv = *(const uint4*)(hb + (((size_t)ng) << 7) + foff);
    *(uint4*)&Zb[m * 136 + 64 + fq3 * 8] = sv;                 // self: k = 64+..
  }
  __syncthreads();

  // ---- Phase B: f16 MFMA. Wave w owns output features j in [16w, 16w+16). ----
  int g = lane >> 4, c = lane & 15;
  const f16x8_t* Wb8 = (const f16x8_t*)Wbf;
  float bj = b2[w * 16 + c];
  f32x4_t accf[4];
#pragma unroll
  for (int mt = 0; mt < 4; ++mt) accf[mt] = (f32x4_t){bj, bj, bj, bj};
#pragma unroll
  for (int ks = 0; ks < 4; ++ks) {
    f16x8_t bfr = Wb8[(w * 4 + ks) * 64 + lane];
#pragma unroll
    for (int mt = 0; mt < 4; ++mt) {
      const f16x8_t* ap = (const f16x8_t*)&Zb[(mt * 16 + c) * 136 + ks * 32 + g * 8];
      accf[mt] = __builtin_amdgcn_mfma_f32_16x16x32_f16(*ap, bfr, accf[mt], 0, 0, 0);
    }
  }
  __syncthreads();

#pragma unroll
  for (int mt = 0; mt < 4; ++mt) {
#pragma unroll
    for (int q = 0; q < 4; ++q) {
      int nodeq = mt * 16 + g * 4 + q;
      Zf[nodeq * 68 + w * 16 + c] = accf[mt][q];
    }
  }
  __syncthreads();

  // ---- Epilogue ----
  int m = lane;
  float* zr = Zf + m * 68 + w * 16;
  float4 z0 = *(const float4*)(zr + 0);
  float4 z1 = *(const float4*)(zr + 4);
  float4 z2 = *(const float4*)(zr + 8);
  float4 z3 = *(const float4*)(zr + 12);
  float acc[16];
  acc[0] = z0.x; acc[1] = z0.y; acc[2] = z0.z; acc[3] = z0.w;
  acc[4] = z1.x; acc[5] = z1.y; acc[6] = z1.z; acc[7] = z1.w;
  acc[8] = z2.x; acc[9] = z2.y; acc[10] = z2.z; acc[11] = z2.w;
  acc[12] = z3.x; acc[13] = z3.y; acc[14] = z3.z; acc[15] = z3.w;

  float s1 = 0.f, s2 = 0.f;
#pragma unroll
  for (int jj = 0; jj < 16; ++jj) { s1 += acc[jj]; s2 += acc[jj] * acc[jj]; }
  red[0][w][m] = s1;
  red[1][w][m] = s2;
  __syncthreads();
  float mu = (red[0][0][m] + red[0][1][m] + red[0][2][m] + red[0][3][m]) * (1.f / 64.f);
  float ex2 = (red[1][0][m] + red[1][1][m] + red[1][2][m] + red[1][3][m]) * (1.f / 64.f);
  float var = fmaxf(ex2 - mu * mu, 0.f);
  float rs = rsqrtf(var + EPS_);

  bool okm = (n0 + m) < N_;
#pragma unroll
  for (int jj = 0; jj < 16; ++jj) {
    float hv = fmaxf((acc[jj] - mu) * rs * g2[w * 16 + jj] + be2[w * 16 + jj], 0.f);
    acc[jj] = okm ? hv : 0.f;
  }
  float4 o0 = {acc[0], acc[1], acc[2], acc[3]};
  float4 o1 = {acc[4], acc[5], acc[6], acc[7]};
  float4 o2 = {acc[8], acc[9], acc[10], acc[11]};
  float4 o3 = {acc[12], acc[13], acc[14], acc[15]};
  *(float4*)(zr + 0) = o0;  *(float4*)(zr + 4) = o1;
  *(float4*)(zr + 8) = o2;  *(float4*)(zr + 12) = o3;
  __syncthreads();

  float cs = 0.f;
#pragma unroll
  for (int ii = 0; ii < 16; ++ii) cs += Zf[(w * 16 + ii) * 68 + lane];
  red[0][w][lane] = cs;
  __syncthreads();
  if (w == 0) {
    float tot = red[0][0][lane] + red[0][1][lane] + red[0][2][lane] + red[0][3][lane];
    atomicAdd(&Hsum[(t * B_ + b) * HG_ + lane], tot);
  }
}

// ---------------- GRU input precompute: GI[t][b][384] ----------------
__global__ void k_gi(const float* __restrict__ Hsum, const float* __restrict__ W_ih,
                     const float* __restrict__ b_ih, float* __restrict__ GI) {
  __shared__ float xv[64];
  int tb = blockIdx.x;
  int tid = threadIdx.x;
  if (tid < 64) xv[tid] = Hsum[tb * 64 + tid] * (1.0f / (float)N_);
  __syncthreads();
  float g = b_ih[tid];
  const float4* W4 = (const float4*)(W_ih + tid * 64);
  const float4* x4 = (const float4*)xv;
#pragma unroll
  for (int q = 0; q < 16; q++) {
    float4 w = W4[q], xq = x4[q];
    g = fmaf(xq.x, w.x, g); g = fmaf(xq.y, w.y, g);
    g = fmaf(xq.z, w.z, g); g = fmaf(xq.w, w.w, g);
  }
  GI[tb * 384 + tid] = g;
}

// ---------------- sequential GRU + head; one block per batch ----------------
__global__ void k_gru(const float* __restrict__ GI, const float* __restrict__ W_hh,
                      const float* __restrict__ b_hh, const float* __restrict__ Wh,
                      const float* __restrict__ bh, float* __restrict__ out) {
  __shared__ float hL[128];
  __shared__ float ghL[384];
  __shared__ float red[128];
  int b = blockIdx.x, tid = threadIdx.x;
  if (tid < 128) hL[tid] = 0.f;
  float bhh = b_hh[tid];
  const float4* W4 = (const float4*)(W_hh + tid * 128);
  for (int t = 0; t < T_; ++t) {
    __syncthreads();
    float g = bhh;
    const float4* h4 = (const float4*)hL;
#pragma unroll
    for (int q = 0; q < 32; q++) {
      float4 w = W4[q], hv = h4[q];
      g = fmaf(hv.x, w.x, g); g = fmaf(hv.y, w.y, g);
      g = fmaf(hv.z, w.z, g); g = fmaf(hv.w, w.w, g);
    }
    ghL[tid] = g;
    __syncthreads();
    float hnew = 0.f;
    if (tid < 128) {
      const float* gi = GI + (t * B_ + b) * 384;
      float rr = 1.f / (1.f + expf(-(gi[tid] + ghL[tid])));
      float zz = 1.f / (1.f + expf(-(gi[128 + tid] + ghL[128 + tid])));
      float nn = tanhf(gi[256 + tid] + rr * ghL[256 + tid]);
      hnew = (1.f - zz) * nn + zz * hL[tid];
    }
    __syncthreads();
    if (tid < 128) hL[tid] = hnew;
  }
  __syncthreads();
  if (tid < 128) red[tid] = hL[tid] * Wh[tid];
  __syncthreads();
  if (tid == 0) {
    float s = bh[0];
    for (int k = 0; k < 128; k++) s += red[k];
    out[b] = s;
  }
}

extern "C" void kernel_launch(void* const* d_in, const int* in_sizes, int n_in,
                              void* d_out, int out_size, void* d_ws, size_t ws_size,
                              hipStream_t stream) {
  const float* x    = (const float*)d_in[0];
  const int*   ei   = (const int*)d_in[1];
  const float* W1l  = (const float*)d_in[2];
  const float* b1   = (const float*)d_in[3];
  const float* W1r  = (const float*)d_in[4];
  const float* g1   = (const float*)d_in[5];
  const float* be1  = (const float*)d_in[6];
  const float* W2l  = (const float*)d_in[7];
  const float* b2   = (const float*)d_in[8];
  const float* W2r  = (const float*)d_in[9];
  const float* g2   = (const float*)d_in[10];
  const float* be2  = (const float*)d_in[11];
  const float* W_ih = (const float*)d_in[12];
  const float* W_hh = (const float*)d_in[13];
  const float* b_ih = (const float*)d_in[14];
  const float* b_hh = (const float*)d_in[15];
  const float* Wh   = (const float*)d_in[16];
  const float* bh   = (const float*)d_in[17];
  float* out = (float*)d_out;

  char* ws = (char*)d_ws;
  size_t off = 0;
  auto alloc = [&](size_t bytes) { void* p = ws + off; off += (bytes + 255) & ~(size_t)255; return p; };
  int*   deg     = (int*)alloc((size_t)N_ * 4);
  int*   row_ptr = (int*)alloc((size_t)(N_ + 1) * 4);
  int*   cursor  = (int*)alloc((size_t)N_ * 4);
  int*   col     = (int*)alloc((size_t)E_ * 4);
  float* ivd     = (float*)alloc((size_t)N_ * 4);
  float* Hsum    = (float*)alloc((size_t)BT_ * HG_ * 4);
  float* GI      = (float*)alloc((size_t)BT_ * 384 * 4);
  unsigned short* Wbf = (unsigned short*)alloc((size_t)4 * 4 * 64 * 8 * 2);
  unsigned short* Wb1 = (unsigned short*)alloc((size_t)4 * 64 * 8 * 2);
  size_t fixed = off;
  unsigned short* h1 = (unsigned short*)(ws + off);

  size_t slab = (size_t)N_ * HG_ * 2;   // 1.28 MB per bt (f16)
  size_t cap = (ws_size > fixed) ? (ws_size - fixed) : 0;
  int CH = (int)(cap / slab);
  if (CH > 64) CH = 64;
  if (CH >= 8) CH &= ~7;
  if (CH < 1) CH = 1;

  int zn = (int)(fixed / 4);
  k_zero<<<(zn + 255) / 256, 256, 0, stream>>>((int*)ws, zn);

  const int* srcp = ei;
  const int* dstp = ei + E_;
  k_deg<<<(E_ + 255) / 256, 256, 0, stream>>>(dstp, deg);
  k_scan<<<1, 256, 0, stream>>>(deg, row_ptr, ivd);
  k_fill<<<(E_ + 255) / 256, 256, 0, stream>>>(srcp, dstp, row_ptr, cursor, col);
  k_prepw<<<32, 256, 0, stream>>>(W2l, W2r, Wbf);
  k_prepw1<<<8, 256, 0, stream>>>(W1l, W1r, Wb1);

  for (int bt0 = 0; bt0 < BT_; bt0 += CH) {
    int c = BT_ - bt0 < CH ? BT_ - bt0 : CH;
    int swz = (c % 8 == 0) ? 1 : 0;
    k_s1<<<c * PB_, 256, 0, stream>>>(x, row_ptr, col, ivd, Wb1, b1, g1, be1,
                                      h1, bt0, swz);
    k_s2<<<c * PB_, 256, 0, stream>>>(h1, row_ptr, col, ivd, Wbf, b2, g2, be2,
                                      Hsum, bt0, swz);
  }
  k_gi<<<BT_, 384, 0, stream>>>(Hsum, W_ih, b_ih, GI);
  k_gru<<<B_, 384, 0, stream>>>(GI, W_hh, b_hh, Wh, bh, out);
}

// Round 9
// 1248.767 us; speedup vs baseline: 1.4780x; 1.3435x over previous
//
#include <hip/hip_runtime.h>
#include <hip/hip_fp16.h>
#include <math.h>

#define B_ 8
#define T_ 32
#define N_ 10000
#define F_ 16
#define E_ 160000
#define HG_ 64
#define HT_ 128
#define BT_ (B_*T_)
#define PB_ 157   // ceil(N/64) node-chunks per bt
#define EPS_ 1e-5f
#define NR_ (N_+1)   // +1 phantom zero row in h1 for branch-free layer-2 gathers
#define NG1_ (PB_*4*4)   // 2512 tile groups for layer 1 (chunk, wave, p4)
#define NG2_ (PB_*4*8)   // 5024 tile groups for layer 2 (chunk, wave, p8)

typedef __attribute__((ext_vector_type(8))) _Float16 f16x8_t;  // 8 f16 = 4 VGPRs
typedef __attribute__((ext_vector_type(4))) float f32x4_t;     // MFMA acc

__device__ inline unsigned short f2h(float f) {
  return __half_as_ushort(__float2half(f));
}
__device__ inline unsigned pkrtz_u(float a, float b) {
  auto h = __builtin_amdgcn_cvt_pkrtz(a, b);
  unsigned u; __builtin_memcpy(&u, &h, 4); return u;
}
__device__ inline unsigned pack2h(float a, float b) {
  __half2 h = __floats2half2_rn(a, b);
  unsigned u; __builtin_memcpy(&u, &h, 4); return u;
}
__device__ inline __half2 u2h(unsigned u) {
  __half2 h; __builtin_memcpy(&h, &u, 4); return h;
}
__device__ inline unsigned h2u(__half2 h) {
  unsigned u; __builtin_memcpy(&u, &h, 4); return u;
}
__device__ inline void bflyh(__half2& a, int m) {
  unsigned u = (unsigned)__shfl_xor((int)h2u(a), m);
  a += u2h(u);
}

// ---------------- CSR build ----------------
__global__ void k_zero(int* p, int n) {
  int i = blockIdx.x * 256 + threadIdx.x;
  if (i < n) p[i] = 0;
}

__global__ void k_deg(const int* __restrict__ dst, int* __restrict__ deg) {
  int e = blockIdx.x * 256 + threadIdx.x;
  if (e < E_) atomicAdd(&deg[dst[e]], 1);
}

__global__ void k_scan(const int* __restrict__ deg, int* __restrict__ row_ptr,
                       float* __restrict__ inv_deg) {
  __shared__ int part[256];
  int tid = threadIdx.x;
  int base = tid * 40;
  int s = 0;
  for (int i = 0; i < 40; i++) { int idx = base + i; if (idx < N_) s += deg[idx]; }
  part[tid] = s;
  __syncthreads();
  if (tid == 0) {
    int run = 0;
    for (int i = 0; i < 256; i++) { int v = part[i]; part[i] = run; run += v; }
  }
  __syncthreads();
  int run = part[tid];
  for (int i = 0; i < 40; i++) {
    int idx = base + i;
    if (idx < N_) {
      row_ptr[idx] = run;
      int d = deg[idx];
      run += d;
      inv_deg[idx] = 1.0f / fmaxf((float)d, 1.0f);
    } else if (idx == N_) {
      row_ptr[N_] = run;
    }
  }
}

__global__ void k_fill(const int* __restrict__ src, const int* __restrict__ dst,
                       const int* __restrict__ row_ptr, int* __restrict__ cursor,
                       int* __restrict__ col) {
  int e = blockIdx.x * 256 + threadIdx.x;
  if (e < E_) {
    int d = dst[e];
    int p = atomicAdd(&cursor[d], 1);
    col[row_ptr[d] + p] = src[e];
  }
}

// ---------------- edge-tile build (graph-only, shared across all bt) ----------
// T1 groups: g = (c*4 + w)*4 + p4; 4 nodes; 16 slots (node2[2]|eo2[2]); rounds
//   = ceil(max4 deg / 4); entry = col*64 (x row bytes) or -64 sentinel.
// T2 groups: g = (c*4 + w)*8 + p8; 2 nodes; 8 slots (nsel[1]|eo2[2]); rounds
//   = ceil(max2 deg / 4); entry = col*128 (h1 row bytes) or N_*128 (phantom).
__global__ void k_trounds1(const int* __restrict__ row_ptr, int* __restrict__ cnt1) {
  int g = blockIdx.x * 256 + threadIdx.x;
  if (g >= NG1_) return;
  int c = g >> 4, w = (g >> 2) & 3, p = g & 3;
  int nb = c * 64 + w * 16 + p * 4;
  int mx = 0;
#pragma unroll
  for (int k = 0; k < 4; ++k) {
    int n = nb + k;
    int d = (n < N_) ? (row_ptr[n + 1] - row_ptr[n]) : 0;
    mx = max(mx, d);
  }
  cnt1[g] = ((mx + 3) >> 2) * 16;
}

__global__ void k_trounds2(const int* __restrict__ row_ptr, int* __restrict__ cnt2) {
  int g = blockIdx.x * 256 + threadIdx.x;
  if (g >= NG2_) return;
  int c = g >> 5, w = (g >> 3) & 3, p = g & 7;
  int nb = c * 64 + w * 16 + p * 2;
  int mx = 0;
#pragma unroll
  for (int k = 0; k < 2; ++k) {
    int n = nb + k;
    int d = (n < N_) ? (row_ptr[n + 1] - row_ptr[n]) : 0;
    mx = max(mx, d);
  }
  cnt2[g] = ((mx + 3) >> 2) * 8;
}

// generic single-block exclusive scan; off[n] = total
__global__ void k_pscan(const int* __restrict__ cnt, int* __restrict__ off, int n) {
  __shared__ int part[256];
  int tid = threadIdx.x;
  int per = (n + 255) / 256;
  int base = tid * per;
  int s = 0;
  for (int i = 0; i < per; i++) { int idx = base + i; if (idx < n) s += cnt[idx]; }
  part[tid] = s;
  __syncthreads();
  if (tid == 0) {
    int run = 0;
    for (int i = 0; i < 256; i++) { int v = part[i]; part[i] = run; run += v; }
    off[n] = run;
  }
  __syncthreads();
  int run = part[tid];
  for (int i = 0; i < per; i++) {
    int idx = base + i;
    if (idx < n) { off[idx] = run; run += cnt[idx]; }
  }
}

__global__ void k_tfill1(const int* __restrict__ row_ptr, const int* __restrict__ col,
                         const int* __restrict__ toff1, int* __restrict__ T1) {
  int idx = blockIdx.x * 256 + threadIdx.x;   // NG1_*16 = 40192
  if (idx >= NG1_ * 16) return;
  int g = idx >> 4, slot = idx & 15;
  int node2 = slot >> 2, eo2 = slot & 3;
  int c = g >> 4, w = (g >> 2) & 3, p = g & 3;
  int n = c * 64 + w * 16 + p * 4 + node2;
  int s0 = 0, d = 0;
  if (n < N_) { s0 = row_ptr[n]; d = row_ptr[n + 1] - s0; }
  int o = toff1[g];
  int nr = (toff1[g + 1] - o) >> 4;
  int* tb = T1 + o + slot;
  for (int r = 0; r < nr; ++r) {
    int e = eo2 + 4 * r;
    tb[r * 16] = (e < d) ? col[s0 + e] * 64 : -64;
  }
}

__global__ void k_tfill2(const int* __restrict__ row_ptr, const int* __restrict__ col,
                         const int* __restrict__ toff2, int* __restrict__ T2) {
  int idx = blockIdx.x * 256 + threadIdx.x;   // NG2_*8 = 40192
  if (idx >= NG2_ * 8) return;
  int g = idx >> 3, slot = idx & 7;
  int nsel = slot >> 2, eo2 = slot & 3;
  int c = g >> 5, w = (g >> 3) & 3, p = g & 7;
  int n = c * 64 + w * 16 + p * 2 + nsel;
  int s0 = 0, d = 0;
  if (n < N_) { s0 = row_ptr[n]; d = row_ptr[n + 1] - s0; }
  int o = toff2[g];
  int nr = (toff2[g + 1] - o) >> 3;
  int* tb = T2 + o + slot;
  for (int r = 0; r < nr; ++r) {
    int e = eo2 + 4 * r;
    tb[r * 8] = (e < d) ? col[s0 + e] * 128 : N_ * 128;
  }
}

// ---------------- weight prep (f16 fragments) ----------------
__global__ void k_prepw(const float* __restrict__ W2l, const float* __restrict__ W2r,
                        unsigned short* __restrict__ Wbf) {
  int idx = blockIdx.x * 256 + threadIdx.x;   // 8192 total
  if (idx >= 4 * 4 * 64 * 8) return;
  int q  = idx & 7;
  int l  = (idx >> 3) & 63;
  int ks = (idx >> 9) & 3;
  int w  = idx >> 11;
  int j = w * 16 + (l & 15);
  int k = ks * 32 + ((l >> 4) * 8) + q;
  float v = (k < 64) ? W2l[j * 64 + k] : W2r[j * 64 + (k - 64)];
  Wbf[idx] = f2h(v);
}

__global__ void k_prepw1(const float* __restrict__ W1l, const float* __restrict__ W1r,
                         unsigned short* __restrict__ Wb1) {
  int idx = blockIdx.x * 256 + threadIdx.x;   // 2048 total
  if (idx >= 4 * 64 * 8) return;
  int q = idx & 7;
  int l = (idx >> 3) & 63;
  int w = idx >> 9;
  int j = w * 16 + (l & 15);
  int k = ((l >> 4) * 8) + q;
  float v = (k < 16) ? W1l[j * 16 + k] : W1r[j * 16 + (k - 16)];
  Wb1[idx] = f2h(v);
}

// ---------------- SAGE layer 1, tile-driven gather + MFMA, f16 ----------------
__launch_bounds__(256, 8)
__global__ void k_sage1t(const float* __restrict__ x, const float* __restrict__ inv_deg,
                         const int* __restrict__ toff1, const int* __restrict__ T1,
                         const unsigned short* __restrict__ Wb1, const float* __restrict__ b1,
                         const float* __restrict__ g1, const float* __restrict__ be1,
                         unsigned short* __restrict__ h1, const float* __restrict__ zrow,
                         int bt0, int CH, int swz) {
  __shared__ __align__(16) unsigned short ZU[64 * 136];   // f16 Z1b[64][40] / f32 Zf[64][68]
  __shared__ float red[2][4][64];
  unsigned short* Z1b = ZU;
  float* Zf = (float*)ZU;
  int i = blockIdx.x;
  int btl, chunk;
  if (swz) {  // pin all blocks of one bt to one XCD
    int xcd = i & 7; int j = i >> 3; int per = CH >> 3;
    btl = xcd * per + j / PB_; chunk = j % PB_;
  } else {
    btl = i / PB_; chunk = i % PB_;
  }
  int bt = bt0 + btl;
  int tid = threadIdx.x;
  int w = __builtin_amdgcn_readfirstlane(tid >> 6);
  int lane = tid & 63;
  int n0 = chunk * 64;
  int node = lane >> 4;        // 0..3
  int eo2 = (lane >> 2) & 3;   // edge slot
  int fq2 = lane & 3;          // feat group (float4)
  const float4* xb = (const float4*)(x + (size_t)bt * (N_ * F_));
  const char* xbF = (const char*)xb + fq2 * 16;
  const char* zF = (const char*)zrow + fq2 * 16;

  // stage inv_deg + tile offsets for this wave
  int nloc = n0 + w * 16 + (lane & 15);
  float ivS = (nloc < N_) ? inv_deg[nloc] : 0.f;
  int gidb = (chunk * 4 + w) * 4;
  int toS = (lane <= 4) ? toff1[gidb + lane] : 0;

  // ---- Phase A ----
  for (int p = 0; p < 4; ++p) {
    int mA = w * 16 + p * 4;
    int nA = n0 + mA;
    float ivMy = __shfl(ivS, p * 4 + node);
    int o0 = __shfl(toS, p), o1 = __shfl(toS, p + 1);
    int nr = (o1 - o0) >> 4;
    const int* tp = T1 + o0 + (lane >> 2);
    float4 a = {0.f, 0.f, 0.f, 0.f};
    int r = 0;
    for (; r + 1 < nr; r += 2) {
      int sa = tp[r * 16], sb = tp[r * 16 + 16];
      const char* pa = (sa >= 0) ? (xbF + sa) : zF;
      const char* pb = (sb >= 0) ? (xbF + sb) : zF;
      float4 va = *(const float4*)pa;
      float4 vb = *(const float4*)pb;
      a.x += va.x; a.y += va.y; a.z += va.z; a.w += va.w;
      a.x += vb.x; a.y += vb.y; a.z += vb.z; a.w += vb.w;
    }
    if (r < nr) {
      int sa = tp[r * 16];
      const char* pa = (sa >= 0) ? (xbF + sa) : zF;
      float4 va = *(const float4*)pa;
      a.x += va.x; a.y += va.y; a.z += va.z; a.w += va.w;
    }
    // butterfly over eo2 (lane bits 2-3)
    a.x += __shfl_xor(a.x, 4);  a.y += __shfl_xor(a.y, 4);
    a.z += __shfl_xor(a.z, 4);  a.w += __shfl_xor(a.w, 4);
    a.x += __shfl_xor(a.x, 8);  a.y += __shfl_xor(a.y, 8);
    a.z += __shfl_xor(a.z, 8);  a.w += __shfl_xor(a.w, 8);
    if (eo2 == 0) {
      uint2 pk;
      pk.x = pkrtz_u(a.x * ivMy, a.y * ivMy);
      pk.y = pkrtz_u(a.z * ivMy, a.w * ivMy);
      *(uint2*)&Z1b[(mA + node) * 40 + fq2 * 4] = pk;          // agg: k = fq2*4..+3
    } else if (eo2 == 1) {
      int nS = nA + node;
      float4 sv = {0.f, 0.f, 0.f, 0.f};
      if (nS < N_) sv = xb[(size_t)nS * 4 + fq2];
      uint2 pk;
      pk.x = pkrtz_u(sv.x, sv.y);
      pk.y = pkrtz_u(sv.z, sv.w);
      *(uint2*)&Z1b[(mA + node) * 40 + 16 + fq2 * 4] = pk;     // self: k = 16+..
    }
  }
  __syncthreads();

  // ---- Phase B: one f16 MFMA per node-tile. Wave w owns j in [16w,16w+16). ----
  int g = lane >> 4, c = lane & 15;
  float bj = b1[w * 16 + c];
  f32x4_t accf[4];
#pragma unroll
  for (int mt = 0; mt < 4; ++mt) accf[mt] = (f32x4_t){bj, bj, bj, bj};
  f16x8_t bfr = ((const f16x8_t*)Wb1)[w * 64 + lane];
#pragma unroll
  for (int mt = 0; mt < 4; ++mt) {
    const f16x8_t* ap = (const f16x8_t*)&Z1b[(mt * 16 + c) * 40 + g * 8];
    accf[mt] = __builtin_amdgcn_mfma_f32_16x16x32_f16(*ap, bfr, accf[mt], 0, 0, 0);
  }
  __syncthreads();   // all waves done reading Z1b before aliased fp32 writes

  // C layout (HW-verified): col = lane&15, row = 4*(lane>>4)+reg.
#pragma unroll
  for (int mt = 0; mt < 4; ++mt) {
#pragma unroll
    for (int q = 0; q < 4; ++q) {
      int nodeq = mt * 16 + g * 4 + q;
      Zf[nodeq * 68 + w * 16 + c] = accf[mt][q];
    }
  }
  __syncthreads();

  // ---- Epilogue: lane = node m; wave w owns j-quarter [16w,16w+16) ----
  int m = lane;
  const float* zr = Zf + m * 68 + w * 16;
  float4 z0 = *(const float4*)(zr + 0);
  float4 z1 = *(const float4*)(zr + 4);
  float4 z2 = *(const float4*)(zr + 8);
  float4 z3 = *(const float4*)(zr + 12);
  float acc[16];
  acc[0] = z0.x; acc[1] = z0.y; acc[2] = z0.z; acc[3] = z0.w;
  acc[4] = z1.x; acc[5] = z1.y; acc[6] = z1.z; acc[7] = z1.w;
  acc[8] = z2.x; acc[9] = z2.y; acc[10] = z2.z; acc[11] = z2.w;
  acc[12] = z3.x; acc[13] = z3.y; acc[14] = z3.z; acc[15] = z3.w;

  float s1 = 0.f, s2 = 0.f;
#pragma unroll
  for (int jj = 0; jj < 16; ++jj) { s1 += acc[jj]; s2 += acc[jj] * acc[jj]; }
  red[0][w][m] = s1;
  red[1][w][m] = s2;
  __syncthreads();
  float mu = (red[0][0][m] + red[0][1][m] + red[0][2][m] + red[0][3][m]) * (1.f / 64.f);
  float ex2 = (red[1][0][m] + red[1][1][m] + red[1][2][m] + red[1][3][m]) * (1.f / 64.f);
  float var = fmaxf(ex2 - mu * mu, 0.f);
  float rs = rsqrtf(var + EPS_);

  int nAbs = n0 + m;
  unsigned short* dst = h1 + ((size_t)btl * NR_ + nAbs) * HG_ + w * 16;
  if (nAbs < N_) {
#pragma unroll
    for (int jj = 0; jj < 16; ++jj)
      acc[jj] = fmaxf((acc[jj] - mu) * rs * g1[w * 16 + jj] + be1[w * 16 + jj], 0.f);
    uint4 pa, pb;
    pa.x = pack2h(acc[0], acc[1]);  pa.y = pack2h(acc[2], acc[3]);
    pa.z = pack2h(acc[4], acc[5]);  pa.w = pack2h(acc[6], acc[7]);
    pb.x = pack2h(acc[8], acc[9]);  pb.y = pack2h(acc[10], acc[11]);
    pb.z = pack2h(acc[12], acc[13]); pb.w = pack2h(acc[14], acc[15]);
    *(uint4*)dst = pa;
    *(uint4*)(dst + 8) = pb;
  } else if (nAbs == N_) {
    uint4 zz = {0, 0, 0, 0};
    *(uint4*)dst = zz;
    *(uint4*)(dst + 8) = zz;
  }
}

// ---------------- SAGE layer 2, tile-driven gather + MFMA, f16 ----------------
__launch_bounds__(256, 8)
__global__ void k_sage2t(const unsigned short* __restrict__ h1, const float* __restrict__ inv_deg,
                         const int* __restrict__ toff2, const int* __restrict__ T2,
                         const unsigned short* __restrict__ Wbf, const float* __restrict__ b2,
                         const float* __restrict__ g2, const float* __restrict__ be2,
                         float* __restrict__ Hsum, int bt0, int CH, int swz) {
  __shared__ __align__(16) unsigned short Zb[64 * 136];   // f16 / aliased fp32
  __shared__ float red[2][4][64];
  float* Zf = (float*)Zb;
  int i = blockIdx.x;
  int btl, chunk;
  if (swz) {
    int xcd = i & 7; int j = i >> 3; int per = CH >> 3;
    btl = xcd * per + j / PB_; chunk = j % PB_;
  } else {
    btl = i / PB_; chunk = i % PB_;
  }
  int bt = bt0 + btl;
  int b = bt / T_, t = bt % T_;
  const char* hb = (const char*)(h1 + (size_t)btl * ((size_t)NR_ * HG_));  // row = 128 B
  int tid = threadIdx.x;
  int w = __builtin_amdgcn_readfirstlane(tid >> 6);
  int lane = tid & 63;
  int n0 = chunk * 64;
  int nsel = lane >> 5;
  int fq3 = lane & 7;
  const char* hbF = hb + fq3 * 16;

  // stage inv_deg + tile offsets for this wave
  int nloc = n0 + w * 16 + (lane & 15);
  float ivS = (nloc < N_) ? inv_deg[nloc] : 0.f;
  int gidb = (chunk * 4 + w) * 8;
  int toS = (lane <= 8) ? toff2[gidb + lane] : 0;

  // ---- Phase A ----
  for (int p = 0; p < 8; ++p) {
    int mA = w * 16 + p * 2;
    float ivMy = __shfl(ivS, p * 2 + nsel);
    int o0 = __shfl(toS, p), o1 = __shfl(toS, p + 1);
    int nr = (o1 - o0) >> 3;
    const int* tp = T2 + o0 + (lane >> 3);
    __half2 a0 = __float2half2_rn(0.f), a1 = a0, a2 = a0, a3 = a0;
    int r = 0;
    for (; r + 1 < nr; r += 2) {
      int sa = tp[r * 8], sb = tp[r * 8 + 8];
      uint4 va = *(const uint4*)(hbF + sa);
      uint4 vb = *(const uint4*)(hbF + sb);
      a0 += u2h(va.x); a1 += u2h(va.y); a2 += u2h(va.z); a3 += u2h(va.w);
      a0 += u2h(vb.x); a1 += u2h(vb.y); a2 += u2h(vb.z); a3 += u2h(vb.w);
    }
    if (r < nr) {
      int sa = tp[r * 8];
      uint4 va = *(const uint4*)(hbF + sa);
      a0 += u2h(va.x); a1 += u2h(va.y); a2 += u2h(va.z); a3 += u2h(va.w);
    }
    // butterfly over eo2 (lane bits 3-4), packed f16
    bflyh(a0, 8);  bflyh(a1, 8);  bflyh(a2, 8);  bflyh(a3, 8);
    bflyh(a0, 16); bflyh(a1, 16); bflyh(a2, 16); bflyh(a3, 16);
    int eo2 = (lane >> 3) & 3;
    if (eo2 == 0) {
      __half2 ivh = __float2half2_rn(ivMy);
      uint4 pk;
      pk.x = h2u(a0 * ivh); pk.y = h2u(a1 * ivh);
      pk.z = h2u(a2 * ivh); pk.w = h2u(a3 * ivh);
      *(uint4*)&Zb[(mA + nsel) * 136 + fq3 * 8] = pk;            // agg: k = fq3*8..+7
    } else if (eo2 == 1) {
      int nS = n0 + mA + nsel;
      int nSc = nS < N_ ? nS : N_;   // phantom zero row
      uint4 sv = *(const uint4*)(hbF + ((size_t)nSc << 7));
      *(uint4*)&Zb[(mA + nsel) * 136 + 64 + fq3 * 8] = sv;       // self: k = 64+..
    }
  }
  __syncthreads();

  // ---- Phase B: f16 MFMA. Wave w owns output features j in [16w, 16w+16). ----
  int g = lane >> 4, c = lane & 15;
  const f16x8_t* Wb8 = (const f16x8_t*)Wbf;
  float bj = b2[w * 16 + c];
  f32x4_t accf[4];
#pragma unroll
  for (int mt = 0; mt < 4; ++mt) accf[mt] = (f32x4_t){bj, bj, bj, bj};
#pragma unroll
  for (int ks = 0; ks < 4; ++ks) {
    f16x8_t bfr = Wb8[(w * 4 + ks) * 64 + lane];
#pragma unroll
    for (int mt = 0; mt < 4; ++mt) {
      const f16x8_t* ap = (const f16x8_t*)&Zb[(mt * 16 + c) * 136 + ks * 32 + g * 8];
      accf[mt] = __builtin_amdgcn_mfma_f32_16x16x32_f16(*ap, bfr, accf[mt], 0, 0, 0);
    }
  }
  __syncthreads();   // all waves done reading Zb before aliased fp32 writes

#pragma unroll
  for (int mt = 0; mt < 4; ++mt) {
#pragma unroll
    for (int q = 0; q < 4; ++q) {
      int nodeq = mt * 16 + g * 4 + q;
      Zf[nodeq * 68 + w * 16 + c] = accf[mt][q];
    }
  }
  __syncthreads();

  // ---- Epilogue ----
  int m = lane;
  float* zr = Zf + m * 68 + w * 16;
  float4 z0 = *(const float4*)(zr + 0);
  float4 z1 = *(const float4*)(zr + 4);
  float4 z2 = *(const float4*)(zr + 8);
  float4 z3 = *(const float4*)(zr + 12);
  float acc[16];
  acc[0] = z0.x; acc[1] = z0.y; acc[2] = z0.z; acc[3] = z0.w;
  acc[4] = z1.x; acc[5] = z1.y; acc[6] = z1.z; acc[7] = z1.w;
  acc[8] = z2.x; acc[9] = z2.y; acc[10] = z2.z; acc[11] = z2.w;
  acc[12] = z3.x; acc[13] = z3.y; acc[14] = z3.z; acc[15] = z3.w;

  float s1 = 0.f, s2 = 0.f;
#pragma unroll
  for (int jj = 0; jj < 16; ++jj) { s1 += acc[jj]; s2 += acc[jj] * acc[jj]; }
  red[0][w][m] = s1;
  red[1][w][m] = s2;
  __syncthreads();
  float mu = (red[0][0][m] + red[0][1][m] + red[0][2][m] + red[0][3][m]) * (1.f / 64.f);
  float ex2 = (red[1][0][m] + red[1][1][m] + red[1][2][m] + red[1][3][m]) * (1.f / 64.f);
  float var = fmaxf(ex2 - mu * mu, 0.f);
  float rs = rsqrtf(var + EPS_);

  bool okm = (n0 + m) < N_;
#pragma unroll
  for (int jj = 0; jj < 16; ++jj) {
    float hv = fmaxf((acc[jj] - mu) * rs * g2[w * 16 + jj] + be2[w * 16 + jj], 0.f);
    acc[jj] = okm ? hv : 0.f;
  }
  float4 o0 = {acc[0], acc[1], acc[2], acc[3]};
  float4 o1 = {acc[4], acc[5], acc[6], acc[7]};
  float4 o2 = {acc[8], acc[9], acc[10], acc[11]};
  float4 o3 = {acc[12], acc[13], acc[14], acc[15]};
  *(float4*)(zr + 0) = o0;  *(float4*)(zr + 4) = o1;
  *(float4*)(zr + 8) = o2;  *(float4*)(zr + 12) = o3;
  __syncthreads();

  float cs = 0.f;
#pragma unroll
  for (int ii = 0; ii < 16; ++ii) cs += Zf[(w * 16 + ii) * 68 + lane];
  red[0][w][lane] = cs;
  __syncthreads();
  if (w == 0) {
    float tot = red[0][0][lane] + red[0][1][lane] + red[0][2][lane] + red[0][3][lane];
    atomicAdd(&Hsum[(t * B_ + b) * HG_ + lane], tot);
  }
}

// ---------------- GRU input precompute: GI[t][b][384] ----------------
__global__ void k_gi(const float* __restrict__ Hsum, const float* __restrict__ W_ih,
                     const float* __restrict__ b_ih, float* __restrict__ GI) {
  __shared__ float xv[64];
  int tb = blockIdx.x;
  int tid = threadIdx.x;
  if (tid < 64) xv[tid] = Hsum[tb * 64 + tid] * (1.0f / (float)N_);
  __syncthreads();
  float g = b_ih[tid];
  const float4* W4 = (const float4*)(W_ih + tid * 64);
  const float4* x4 = (const float4*)xv;
#pragma unroll
  for (int q = 0; q < 16; q++) {
    float4 w = W4[q], xq = x4[q];
    g = fmaf(xq.x, w.x, g); g = fmaf(xq.y, w.y, g);
    g = fmaf(xq.z, w.z, g); g = fmaf(xq.w, w.w, g);
  }
  GI[tb * 384 + tid] = g;
}

// ---------------- sequential GRU + head; one block per batch ----------------
__global__ void k_gru(const float* __restrict__ GI, const float* __restrict__ W_hh,
                      const float* __restrict__ b_hh, const float* __restrict__ Wh,
                      const float* __restrict__ bh, float* __restrict__ out) {
  __shared__ float hL[128];
  __shared__ float ghL[384];
  __shared__ float red[128];
  int b = blockIdx.x, tid = threadIdx.x;
  if (tid < 128) hL[tid] = 0.f;
  float bhh = b_hh[tid];
  const float4* W4 = (const float4*)(W_hh + tid * 128);
  for (int t = 0; t < T_; ++t) {
    __syncthreads();
    float g = bhh;
    const float4* h4 = (const float4*)hL;
#pragma unroll
    for (int q = 0; q < 32; q++) {
      float4 w = W4[q], hv = h4[q];
      g = fmaf(hv.x, w.x, g); g = fmaf(hv.y, w.y, g);
      g = fmaf(hv.z, w.z, g); g = fmaf(hv.w, w.w, g);
    }
    ghL[tid] = g;
    __syncthreads();
    float hnew = 0.f;
    if (tid < 128) {
      const float* gi = GI + (t * B_ + b) * 384;
      float rr = 1.f / (1.f + expf(-(gi[tid] + ghL[tid])));
      float zz = 1.f / (1.f + expf(-(gi[128 + tid] + ghL[128 + tid])));
      float nn = tanhf(gi[256 + tid] + rr * ghL[256 + tid]);
      hnew = (1.f - zz) * nn + zz * hL[tid];
    }
    __syncthreads();
    if (tid < 128) hL[tid] = hnew;
  }
  __syncthreads();
  if (tid < 128) red[tid] = hL[tid] * Wh[tid];
  __syncthreads();
  if (tid == 0) {
    float s = bh[0];
    for (int k = 0; k < 128; k++) s += red[k];
    out[b] = s;
  }
}

extern "C" void kernel_launch(void* const* d_in, const int* in_sizes, int n_in,
                              void* d_out, int out_size, void* d_ws, size_t ws_size,
                              hipStream_t stream) {
  const float* x    = (const float*)d_in[0];
  const int*   ei   = (const int*)d_in[1];
  const float* W1l  = (const float*)d_in[2];
  const float* b1   = (const float*)d_in[3];
  const float* W1r  = (const float*)d_in[4];
  const float* g1   = (const float*)d_in[5];
  const float* be1  = (const float*)d_in[6];
  const float* W2l  = (const float*)d_in[7];
  const float* b2   = (const float*)d_in[8];
  const float* W2r  = (const float*)d_in[9];
  const float* g2   = (const float*)d_in[10];
  const float* be2  = (const float*)d_in[11];
  const float* W_ih = (const float*)d_in[12];
  const float* W_hh = (const float*)d_in[13];
  const float* b_ih = (const float*)d_in[14];
  const float* b_hh = (const float*)d_in[15];
  const float* Wh   = (const float*)d_in[16];
  const float* bh   = (const float*)d_in[17];
  float* out = (float*)d_out;

  char* ws = (char*)d_ws;
  size_t off = 0;
  auto alloc = [&](size_t bytes) { void* p = ws + off; off += (bytes + 255) & ~(size_t)255; return p; };
  int*   deg     = (int*)alloc((size_t)N_ * 4);
  int*   row_ptr = (int*)alloc((size_t)(N_ + 1) * 4);
  int*   cursor  = (int*)alloc((size_t)N_ * 4);
  int*   col     = (int*)alloc((size_t)E_ * 4);
  float* ivd     = (float*)alloc((size_t)N_ * 4);
  float* Hsum    = (float*)alloc((size_t)BT_ * HG_ * 4);
  float* GI      = (float*)alloc((size_t)BT_ * 384 * 4);
  unsigned short* Wbf = (unsigned short*)alloc((size_t)4 * 4 * 64 * 8 * 2);
  unsigned short* Wb1 = (unsigned short*)alloc((size_t)4 * 64 * 8 * 2);
  float* zrowp   = (float*)alloc(256);
  int*   cnt1    = (int*)alloc((size_t)NG1_ * 4);
  int*   cnt2    = (int*)alloc((size_t)NG2_ * 4);
  int*   toff1   = (int*)alloc((size_t)(NG1_ + 1) * 4);
  int*   toff2   = (int*)alloc((size_t)(NG2_ + 1) * 4);
  // tile bounds: T1 <= (E/4 + NG1_)*16, T2 <= (E/4 + NG2_)*8 entries
  int*   T1      = (int*)alloc(((size_t)E_ / 4 + NG1_) * 16 * 4);   // ~2.9 MB
  int*   T2      = (int*)alloc(((size_t)E_ / 4 + NG2_) * 8 * 4);    // ~1.6 MB
  size_t fixed = off;
  unsigned short* h1 = (unsigned short*)(ws + off);

  size_t slab = (size_t)NR_ * HG_ * 2;   // f16 h1, N+1 rows per bt
  size_t cap = (ws_size > fixed) ? (ws_size - fixed) : 0;
  int CH = (int)(cap / slab);
  if (CH > 64) CH = 64;
  if (CH >= 8) CH &= ~7;
  if (CH < 1) CH = 1;

  int zn = (int)(fixed / 4);
  k_zero<<<(zn + 255) / 256, 256, 0, stream>>>((int*)ws, zn);

  const int* srcp = ei;
  const int* dstp = ei + E_;
  k_deg<<<(E_ + 255) / 256, 256, 0, stream>>>(dstp, deg);
  k_scan<<<1, 256, 0, stream>>>(deg, row_ptr, ivd);
  k_fill<<<(E_ + 255) / 256, 256, 0, stream>>>(srcp, dstp, row_ptr, cursor, col);
  k_trounds1<<<(NG1_ + 255) / 256, 256, 0, stream>>>(row_ptr, cnt1);
  k_trounds2<<<(NG2_ + 255) / 256, 256, 0, stream>>>(row_ptr, cnt2);
  k_pscan<<<1, 256, 0, stream>>>(cnt1, toff1, NG1_);
  k_pscan<<<1, 256, 0, stream>>>(cnt2, toff2, NG2_);
  k_tfill1<<<(NG1_ * 16 + 255) / 256, 256, 0, stream>>>(row_ptr, col, toff1, T1);
  k_tfill2<<<(NG2_ * 8 + 255) / 256, 256, 0, stream>>>(row_ptr, col, toff2, T2);
  k_prepw<<<32, 256, 0, stream>>>(W2l, W2r, Wbf);
  k_prepw1<<<8, 256, 0, stream>>>(W1l, W1r, Wb1);

  for (int bt0 = 0; bt0 < BT_; bt0 += CH) {
    int c = BT_ - bt0 < CH ? BT_ - bt0 : CH;
    int swz = (c % 8 == 0) ? 1 : 0;
    k_sage1t<<<c * PB_, 256, 0, stream>>>(x, ivd, toff1, T1, Wb1, b1, g1, be1,
                                          h1, zrowp, bt0, c, swz);
    k_sage2t<<<c * PB_, 256, 0, stream>>>(h1, ivd, toff2, T2, Wbf, b2, g2, be2,
                                          Hsum, bt0, c, swz);
  }
  k_gi<<<BT_, 384, 0, stream>>>(Hsum, W_ih, b_ih, GI);
  k_gru<<<B_, 384, 0, stream>>>(GI, W_hh, b_hh, Wh, bh, out);
}